// Round 2
// 2174.679 us; speedup vs baseline: 2.2889x; 2.2889x over previous
//
#include <hip/hip_runtime.h>
#include <math.h>

// Problem constants
#define BATCH 1
#define CH 256
#define SEQ 512
#define DIN 256
#define DM 256           // d_model
#define DH 1024          // 4*D
#define MTOT (CH*SEQ)    // 131072 rows
#define ELEMS ((size_t)MTOT*DM)       // 33554432
#define SD (SEQ*DM)      // 131072 per-channel activation elems
#define EPS 1e-5f

typedef _Float16 f16;
using f16x8 = __attribute__((ext_vector_type(8))) _Float16;
using f16x4 = __attribute__((ext_vector_type(4))) _Float16;
using f32x4 = __attribute__((ext_vector_type(4))) float;

// ---------------------------------------------------------------------------
// Split-precision MFMA GEMM:  C = alpha * (A @ B) (+bias)(+relu)(+accum)
// A, B logically fp32, represented as f16 hi/lo planes (or raw fp32 for A when
// AFP32=1, split on the fly during staging).  Computed as
//   Ahi*Bhi + Ahi*Blo + Alo*Bhi   (fp32 MFMA accumulate; error ~2^-22)
// B is ALWAYS physically [N,K] row-major (pre-transposed), so both A and B
// tiles stage as contiguous 8-half rows into [outer][k] LDS (+8 pad).
// 128x128 tile, BK=32, 256 threads = 4 waves, each wave 64x64 via 4x4 frags
// of v_mfma_f32_16x16x32_f16.  Output: fp32 (Cf) or split planes (Ch/Cl).
// ---------------------------------------------------------------------------
template<int AFP32>
__global__ __launch_bounds__(256) void gemm_mfma(
    const void* __restrict__ A0, const f16* __restrict__ A1,
    const f16* __restrict__ B0, const f16* __restrict__ B1,
    float* __restrict__ Cf, f16* __restrict__ Ch, f16* __restrict__ Cl,
    const float* __restrict__ bias,
    int M, int N, int K, int lda, int ldb, int ldc,
    long sA, long sB, long sC, float alpha, int relu, int accum)
{
    const int bz = blockIdx.z;
    const float* Af = nullptr; const f16* Ahi = nullptr; const f16* Alo = nullptr;
    if constexpr (AFP32) {
        Af = (const float*)A0 + (long)bz * sA;
    } else {
        Ahi = (const f16*)A0 + (long)bz * sA;
        Alo = A1 + (long)bz * sA;
    }
    const f16* Bhi = B0 + (long)bz * sB;
    const f16* Blo = B1 + (long)bz * sB;

    __shared__ f16 Ah[128][40];   // +8 pad
    __shared__ f16 Al[128][40];
    __shared__ f16 Bh[128][40];
    __shared__ f16 Bl[128][40];

    const int tid = threadIdx.x;
    const int m0 = blockIdx.y * 128;
    const int n0 = blockIdx.x * 128;
    const int lane = tid & 63;
    const int wave = tid >> 6;
    const int wm = (wave >> 1) * 64;
    const int wn = (wave & 1) * 64;
    const int lr = lane & 15;          // fragment row (A) / col (B,D)
    const int lk = (lane >> 4) * 8;    // fragment k offset

    const int sr = tid >> 2;           // staging row 0..63 (two passes)
    const int sk = (tid & 3) * 8;      // staging k offset 0,8,16,24

    f32x4 acc[4][4];
    #pragma unroll
    for (int i = 0; i < 4; i++)
        #pragma unroll
        for (int j = 0; j < 4; j++)
            #pragma unroll
            for (int q = 0; q < 4; q++) acc[i][j][q] = 0.f;

    for (int k0 = 0; k0 < K; k0 += 32) {
        #pragma unroll
        for (int p = 0; p < 2; p++) {
            const int row = sr + p * 64;
            if constexpr (AFP32) {
                const float* s = Af + (long)(m0 + row) * lda + k0 + sk;
                float4 v0 = *(const float4*)s;
                float4 v1 = *(const float4*)(s + 4);
                float vv[8] = {v0.x, v0.y, v0.z, v0.w, v1.x, v1.y, v1.z, v1.w};
                f16x8 hi, lo;
                #pragma unroll
                for (int e = 0; e < 8; e++) {
                    f16 h = (f16)vv[e];
                    hi[e] = h;
                    lo[e] = (f16)(vv[e] - (float)h);
                }
                *(f16x8*)&Ah[row][sk] = hi;
                *(f16x8*)&Al[row][sk] = lo;
            } else {
                *(f16x8*)&Ah[row][sk] = *(const f16x8*)(Ahi + (long)(m0 + row) * lda + k0 + sk);
                *(f16x8*)&Al[row][sk] = *(const f16x8*)(Alo + (long)(m0 + row) * lda + k0 + sk);
            }
            *(f16x8*)&Bh[row][sk] = *(const f16x8*)(Bhi + (long)(n0 + row) * ldb + k0 + sk);
            *(f16x8*)&Bl[row][sk] = *(const f16x8*)(Blo + (long)(n0 + row) * ldb + k0 + sk);
        }
        __syncthreads();

        f16x8 ah[4], al[4];
        #pragma unroll
        for (int i = 0; i < 4; i++) {
            ah[i] = *(const f16x8*)&Ah[wm + i * 16 + lr][lk];
            al[i] = *(const f16x8*)&Al[wm + i * 16 + lr][lk];
        }
        #pragma unroll
        for (int j = 0; j < 4; j++) {
            f16x8 bh = *(const f16x8*)&Bh[wn + j * 16 + lr][lk];
            f16x8 bl = *(const f16x8*)&Bl[wn + j * 16 + lr][lk];
            #pragma unroll
            for (int i = 0; i < 4; i++) {
                acc[i][j] = __builtin_amdgcn_mfma_f32_16x16x32_f16(ah[i], bh, acc[i][j], 0, 0, 0);
                acc[i][j] = __builtin_amdgcn_mfma_f32_16x16x32_f16(ah[i], bl, acc[i][j], 0, 0, 0);
                acc[i][j] = __builtin_amdgcn_mfma_f32_16x16x32_f16(al[i], bh, acc[i][j], 0, 0, 0);
            }
        }
        __syncthreads();
    }

    // Epilogue. D layout (verified): col = lane&15, row = (lane>>4)*4 + reg.
    float* Cfb = Cf ? Cf + (long)bz * sC : nullptr;
    f16* Chb = Ch ? Ch + (long)bz * sC : nullptr;
    f16* Clb = Cl ? Cl + (long)bz * sC : nullptr;
    const int rq = (lane >> 4) * 4;
    #pragma unroll
    for (int i = 0; i < 4; i++) {
        #pragma unroll
        for (int j = 0; j < 4; j++) {
            const int ncol = n0 + wn + j * 16 + lr;
            const float bv = bias ? bias[ncol] : 0.f;
            #pragma unroll
            for (int q = 0; q < 4; q++) {
                const int mrow = m0 + wm + i * 16 + rq + q;
                float v = acc[i][j][q] * alpha + bv;
                if (relu) v = fmaxf(v, 0.f);
                const long idx = (long)mrow * ldc + ncol;
                if (Cfb) {
                    if (accum) v += Cfb[idx];
                    Cfb[idx] = v;
                } else {
                    f16 h = (f16)v;
                    Chb[idx] = h;
                    Clb[idx] = (f16)(v - (float)h);
                }
            }
        }
    }
}

// ---------------------------------------------------------------------------
// Weight convert: W [K,N] fp32 -> hi/lo f16 planes, transposed to [N,K].
// ---------------------------------------------------------------------------
__global__ __launch_bounds__(256) void wsplit_t(
    const float* __restrict__ w, f16* __restrict__ hi, f16* __restrict__ lo,
    int K, int N)
{
    int i = blockIdx.x * 256 + threadIdx.x;   // index over output [N,K]
    if (i >= N * K) return;
    int n = i / K, k = i - n * K;
    float v = w[(long)k * N + n];
    f16 h = (f16)v;
    hi[i] = h;
    lo[i] = (f16)(v - (float)h);
}

// ---------------------------------------------------------------------------
// LayerNorm over last dim (256): reads fp32 x, writes f16 hi/lo planes.
// ---------------------------------------------------------------------------
__global__ __launch_bounds__(256) void layernorm_split(
    const float* __restrict__ x, const float* __restrict__ g,
    const float* __restrict__ b, f16* __restrict__ nhi, f16* __restrict__ nlo)
{
    int tid = threadIdx.x;
    long row = (long)blockIdx.x * 4 + (tid >> 6);
    int lane = tid & 63;
    float4 v = ((const float4*)(x + row * DM))[lane];
    float s = v.x + v.y + v.z + v.w;
    float q = v.x * v.x + v.y * v.y + v.z * v.z + v.w * v.w;
    #pragma unroll
    for (int off = 32; off > 0; off >>= 1) {
        s += __shfl_xor(s, off);
        q += __shfl_xor(q, off);
    }
    float mu = s * (1.f / DM);
    float var = q * (1.f / DM) - mu * mu;
    float rs = rsqrtf(var + EPS);
    float4 gg = ((const float4*)g)[lane];
    float4 bb = ((const float4*)b)[lane];
    float o[4];
    o[0] = (v.x - mu) * rs * gg.x + bb.x;
    o[1] = (v.y - mu) * rs * gg.y + bb.y;
    o[2] = (v.z - mu) * rs * gg.z + bb.z;
    o[3] = (v.w - mu) * rs * gg.w + bb.w;
    f16x4 hi, lo;
    #pragma unroll
    for (int e = 0; e < 4; e++) {
        f16 h = (f16)o[e];
        hi[e] = h;
        lo[e] = (f16)(o[e] - (float)h);
    }
    ((f16x4*)(nhi + row * DM))[lane] = hi;
    ((f16x4*)(nlo + row * DM))[lane] = lo;
}

// ---------------------------------------------------------------------------
// Per-channel transpose of split planes: [S,D] -> [D,S], both hi and lo.
// ---------------------------------------------------------------------------
__global__ __launch_bounds__(256) void transpose_split(
    const f16* __restrict__ shi, const f16* __restrict__ slo,
    f16* __restrict__ dhi, f16* __restrict__ dlo)
{
    __shared__ f16 tl[2][64][72];
    const int c = blockIdx.z;
    const int d0 = blockIdx.x * 64;
    const int s0 = blockIdx.y * 64;
    const int t = threadIdx.x;
    const int rr = t >> 3;           // 0..31
    const int cc = (t & 7) * 8;
    const long base = (long)c * SD;
    #pragma unroll
    for (int p = 0; p < 2; p++) {
        int i = rr + p * 32;
        *(f16x8*)&tl[0][i][cc] = *(const f16x8*)(shi + base + (long)(s0 + i) * DM + d0 + cc);
        *(f16x8*)&tl[1][i][cc] = *(const f16x8*)(slo + base + (long)(s0 + i) * DM + d0 + cc);
    }
    __syncthreads();
    #pragma unroll
    for (int p = 0; p < 2; p++) {
        int i = rr + p * 32;         // d-local
        f16x8 vh, vl;
        #pragma unroll
        for (int e = 0; e < 8; e++) {
            vh[e] = tl[0][cc + e][i];
            vl[e] = tl[1][cc + e][i];
        }
        *(f16x8*)(dhi + base + (long)(d0 + i) * SEQ + s0 + cc) = vh;
        *(f16x8*)(dlo + base + (long)(d0 + i) * SEQ + s0 + cc) = vl;
    }
}

// ---------------------------------------------------------------------------
// Row softmax over width 512, in place.
// ---------------------------------------------------------------------------
__global__ __launch_bounds__(256) void softmax_k(float* __restrict__ a)
{
    int tid = threadIdx.x;
    long row = (long)blockIdx.x * 4 + (tid >> 6);
    int lane = tid & 63;
    float4* r = (float4*)(a + row * SEQ);
    float4 v0 = r[lane];
    float4 v1 = r[lane + 64];
    float m = fmaxf(fmaxf(fmaxf(v0.x, v0.y), fmaxf(v0.z, v0.w)),
                    fmaxf(fmaxf(v1.x, v1.y), fmaxf(v1.z, v1.w)));
    #pragma unroll
    for (int off = 32; off > 0; off >>= 1) m = fmaxf(m, __shfl_xor(m, off));
    v0.x = expf(v0.x - m); v0.y = expf(v0.y - m);
    v0.z = expf(v0.z - m); v0.w = expf(v0.w - m);
    v1.x = expf(v1.x - m); v1.y = expf(v1.y - m);
    v1.z = expf(v1.z - m); v1.w = expf(v1.w - m);
    float s = v0.x + v0.y + v0.z + v0.w + v1.x + v1.y + v1.z + v1.w;
    #pragma unroll
    for (int off = 32; off > 0; off >>= 1) s += __shfl_xor(s, off);
    float inv = 1.f / s;
    v0.x *= inv; v0.y *= inv; v0.z *= inv; v0.w *= inv;
    v1.x *= inv; v1.y *= inv; v1.z *= inv; v1.w *= inv;
    r[lane] = v0;
    r[lane + 64] = v1;
}

// ---------------------------------------------------------------------------
// Per-channel mean of h.
// ---------------------------------------------------------------------------
__global__ __launch_bounds__(256) void channel_mean_k(
    const float* __restrict__ h, float* __restrict__ y)
{
    __shared__ float red[256];
    int c = blockIdx.x;
    int tid = threadIdx.x;
    const float4* p = (const float4*)(h + (long)c * SEQ * DM);
    float s = 0.f;
    for (int i = tid; i < (SEQ * DM) / 4; i += 256) {
        float4 v = p[i];
        s += v.x + v.y + v.z + v.w;
    }
    red[tid] = s;
    __syncthreads();
    for (int off = 128; off > 0; off >>= 1) {
        if (tid < off) red[tid] += red[tid + off];
        __syncthreads();
    }
    if (tid == 0) y[c] = red[0] * (1.f / (SEQ * DM));
}

// ---------------------------------------------------------------------------
// SE MLP.
// ---------------------------------------------------------------------------
__global__ __launch_bounds__(256) void se_mlp_k(
    const float* __restrict__ y,
    const float* __restrict__ w1, const float* __restrict__ b1,
    const float* __restrict__ w2, const float* __restrict__ b2,
    float* __restrict__ g)
{
    __shared__ float z[16];
    int tid = threadIdx.x;
    if (tid < 16) {
        float s = b1[tid];
        for (int k = 0; k < CH; k++) s += y[k] * w1[k * 16 + tid];
        z[tid] = fmaxf(s, 0.f);
    }
    __syncthreads();
    float s = b2[tid];
    #pragma unroll
    for (int j = 0; j < 16; j++) s += z[j] * w2[j * CH + tid];
    g[tid] = 1.f / (1.f + expf(-s));
}

// ---------------------------------------------------------------------------
// Final: out = h * g[c] + x   (in place over h)
// ---------------------------------------------------------------------------
__global__ __launch_bounds__(256) void finalize_k(
    const float* __restrict__ h, const float* __restrict__ x,
    const float* __restrict__ g, float* __restrict__ out)
{
    long i = (long)blockIdx.x * 256 + threadIdx.x;   // float4 index
    int c = (int)(i >> 15) & 255;                    // i*4 / (S*D=2^17)
    float gv = g[c];
    float4 hv = ((const float4*)h)[i];
    float4 xv = ((const float4*)x)[i];
    float4 o;
    o.x = hv.x * gv + xv.x;
    o.y = hv.y * gv + xv.y;
    o.z = hv.z * gv + xv.z;
    o.w = hv.w * gv + xv.w;
    ((float4*)out)[i] = o;
}

// ---------------------------------------------------------------------------
extern "C" void kernel_launch(void* const* d_in, const int* in_sizes, int n_in,
                              void* d_out, int out_size, void* d_ws, size_t ws_size,
                              hipStream_t stream)
{
    const float* input = (const float*)d_in[0];
    const float* W_emb = (const float*)d_in[1];
    const float* b_emb = (const float*)d_in[2];
    const float* ln_g  = (const float*)d_in[3];
    const float* ln_b  = (const float*)d_in[4];
    const float* W1    = (const float*)d_in[5];
    const float* b1    = (const float*)d_in[6];
    const float* W2    = (const float*)d_in[7];
    const float* b2    = (const float*)d_in[8];
    const float* seW1  = (const float*)d_in[9];
    const float* seB1  = (const float*)d_in[10];
    const float* seW2  = (const float*)d_in[11];
    const float* seB2  = (const float*)d_in[12];

    float* outp = (float*)d_out;            // [B,C,S,D] (h lives here too)
    float* attn = outp + ELEMS;             // [B,C,S,S] fp32 (output #2)

    // ---- workspace: EXACTLY 3*ELEMS + 512 floats (<= old kernel's proven min) ----
    float* ws = (float*)d_ws;
    float* xbuf = ws;                               // unit0: fp32 residual
    f16* nA_hi  = (f16*)(ws + ELEMS);               // unit1: n planes -> later o planes
    f16* nA_lo  = nA_hi + ELEMS;
    f16* u2     = (f16*)(ws + 2 * ELEMS);           // unit2: time-shared (2*ELEMS halves)
    float* yg   = ws + 3 * ELEMS;                   // y[256], g[256]

    // unit2 phase A: wembT planes (dead after emb GEMM)
    f16* wembT_hi = u2;                             // [DM,DIN] 65536 halves each
    f16* wembT_lo = u2 + 65536;
    // unit2 phase B: nT planes (dead after PV GEMM)
    f16* nT_hi = u2;
    f16* nT_lo = u2 + ELEMS;
    // unit2 phase C: w1T/w2T planes + FFN hidden chunk
    f16* w1T_hi = u2;                               // [DH,DM] 262144 each
    f16* w1T_lo = w1T_hi + 262144;
    f16* w2T_hi = w1T_lo + 262144;                  // [DM,DH] 262144 each
    f16* w2T_lo = w2T_hi + 262144;
    f16* t_hi   = w2T_lo + 262144;                  // chunk planes
    const int rc = 65536;                           // 2 chunks cover MTOT
    f16* t_lo   = t_hi + (long)rc * DM;             // ends at 34,603,008 < 2*ELEMS halves

    // o planes reuse unit1 (nA dead after scores GEMM)
    f16* o_hi = nA_hi;
    f16* o_lo = nA_lo;

    // 0) split+transpose W_emb into unit2
    wsplit_t<<<(DIN * DM + 255) / 256, 256, 0, stream>>>(W_emb, wembT_hi, wembT_lo, DIN, DM);

    // 1) x = input @ W_emb + b_emb   (A fp32 split on the fly)
    gemm_mfma<1><<<dim3(DM / 128, MTOT / 128, 1), 256, 0, stream>>>(
        input, nullptr, wembT_hi, wembT_lo, xbuf, nullptr, nullptr, b_emb,
        MTOT, DM, DIN, DIN, DIN, DM, 0, 0, 0, 1.f, 0, 0);

    // 2) n = LayerNorm(x)  -> split planes (unit1)
    layernorm_split<<<MTOT / 4, 256, 0, stream>>>(xbuf, ln_g, ln_b, nA_hi, nA_lo);

    // 2b) n^T planes (unit2, overwrites dead wembT)
    transpose_split<<<dim3(DM / 64, SEQ / 64, CH), 256, 0, stream>>>(
        nA_hi, nA_lo, nT_hi, nT_lo);

    // 3a) scores = n @ n^T / 16   (B phys [N,K] == nA itself)
    gemm_mfma<0><<<dim3(SEQ / 128, SEQ / 128, CH), 256, 0, stream>>>(
        nA_hi, nA_lo, nA_hi, nA_lo, attn, nullptr, nullptr, nullptr,
        SEQ, SEQ, DM, DM, DM, SEQ, (long)SD, (long)SD, (long)SEQ * SEQ,
        1.f / 16.f, 0, 0);

    // 3b) softmax rows (in place, fp32 in d_out)
    softmax_k<<<(CH * SEQ) / 4, 256, 0, stream>>>(attn);

    // 3c) o = attn @ n   (A = attn fp32 split on the fly; B = nT planes)
    //     writes o planes into unit1 (nA dead; reads only attn + nT)
    gemm_mfma<1><<<dim3(DM / 128, SEQ / 128, CH), 256, 0, stream>>>(
        attn, nullptr, nT_hi, nT_lo, nullptr, o_hi, o_lo, nullptr,
        SEQ, DM, SEQ, SEQ, SEQ, DM, (long)SEQ * SEQ, (long)SD, (long)SD,
        1.f, 0, 0);

    // 3d) split W1/W2 into unit2 (nT dead now)
    wsplit_t<<<(DM * DH + 255) / 256, 256, 0, stream>>>(W1, w1T_hi, w1T_lo, DM, DH);
    wsplit_t<<<(DH * DM + 255) / 256, 256, 0, stream>>>(W2, w2T_hi, w2T_lo, DH, DM);

    // 4) FFN: h = relu(o @ W1 + b1) @ W2 + b2   (hidden chunked by 256, h -> outp)
    for (int r0 = 0; r0 < MTOT; r0 += rc) {
        int rws = (MTOT - r0 < rc) ? (MTOT - r0) : rc;
        for (int hc = 0; hc < 4; hc++) {
            // t = relu(o_rows @ W1[:, hc*256:+256] + b1_chunk)  -> split planes
            gemm_mfma<0><<<dim3(2, rws / 128, 1), 256, 0, stream>>>(
                o_hi + (long)r0 * DM, o_lo + (long)r0 * DM,
                w1T_hi + (long)hc * 256 * DM, w1T_lo + (long)hc * 256 * DM,
                nullptr, t_hi, t_lo, b1 + hc * 256,
                rws, 256, DM, DM, DM, 256, 0, 0, 0, 1.f, 1, 0);
            // h += t @ W2[hc*256:+256, :]  (+b2 on first chunk)
            gemm_mfma<0><<<dim3(2, rws / 128, 1), 256, 0, stream>>>(
                t_hi, t_lo, w2T_hi + hc * 256, w2T_lo + hc * 256,
                outp + (long)r0 * DM, nullptr, nullptr, (hc == 0) ? b2 : nullptr,
                rws, DM, 256, 256, DH, DM, 0, 0, 0, 1.f, 0, (hc > 0) ? 1 : 0);
        }
    }

    // 5) SE gate (h is in outp)
    channel_mean_k<<<CH, 256, 0, stream>>>(outp, yg);
    se_mlp_k<<<1, 256, 0, stream>>>(yg, seW1, seB1, seW2, seB2, yg + 256);

    // 6) out = h * g + x  (in place over outp)
    finalize_k<<<(unsigned)(ELEMS / 4 / 256), 256, 0, stream>>>(
        outp, xbuf, yg + 256, outp);
}

// Round 3
// 2134.238 us; speedup vs baseline: 2.3323x; 1.0189x over previous
//
#include <hip/hip_runtime.h>
#include <math.h>

// Problem constants
#define BATCH 1
#define CH 256
#define SEQ 512
#define DIN 256
#define DM 256           // d_model
#define DH 1024          // 4*D
#define MTOT (CH*SEQ)    // 131072 rows
#define ELEMS ((size_t)MTOT*DM)       // 33554432
#define SD (SEQ*DM)      // 131072 per-channel activation elems
#define EPS 1e-5f

typedef _Float16 f16;
using f16x8 = __attribute__((ext_vector_type(8))) _Float16;
using f16x4 = __attribute__((ext_vector_type(4))) _Float16;
using f32x4 = __attribute__((ext_vector_type(4))) float;

// async 16B global->LDS (dest = wave-uniform base + lane*16)
__device__ __forceinline__ void gld16(const f16* g, f16* l)
{
    __builtin_amdgcn_global_load_lds(
        (const __attribute__((address_space(1))) void*)g,
        (__attribute__((address_space(3))) void*)l, 16, 0, 0);
}

// swizzled LDS half-offset for tile [128 rows][32 halves]: chunk c (16B) of row r
// stored at chunk (c ^ (r&3))  -> byte = r*64 + (c^(r&3))*16
#define SWZ(r, c) (((r) << 5) + (((c) ^ ((r) & 3)) << 3))

// ---------------------------------------------------------------------------
// Split-precision MFMA GEMM:  C = alpha * (A @ B) (+bias)(+relu)(+accum)
// A, B logically fp32 as f16 hi/lo planes (AFP32=1: A raw fp32, split on the
// fly).  Computed as Ahi*Bhi + Ahi*Blo + Alo*Bhi (fp32 MFMA accumulate).
// B phys [N,K] row-major.  128x128 tile, BK=32, 4 waves, 16x16x32 f16 MFMA.
// Staging via global_load_lds w=16 into XOR-swizzled linear LDS tiles.
// ---------------------------------------------------------------------------
template<int AFP32>
__global__ __launch_bounds__(256) void gemm_mfma(
    const void* __restrict__ A0, const f16* __restrict__ A1,
    const f16* __restrict__ B0, const f16* __restrict__ B1,
    float* __restrict__ Cf, f16* __restrict__ Ch, f16* __restrict__ Cl,
    const float* __restrict__ bias,
    int M, int N, int K, int lda, int ldb, int ldc,
    long sA, long sB, long sC, float alpha, int relu, int accum)
{
    const int bz = blockIdx.z;
    const float* Af = nullptr; const f16* Ahi = nullptr; const f16* Alo = nullptr;
    if constexpr (AFP32) {
        Af = (const float*)A0 + (long)bz * sA;
    } else {
        Ahi = (const f16*)A0 + (long)bz * sA;
        Alo = A1 + (long)bz * sA;
    }
    const f16* Bhi = B0 + (long)bz * sB;
    const f16* Blo = B1 + (long)bz * sB;

    __shared__ f16 AhL[128 * 32];
    __shared__ f16 AlL[128 * 32];
    __shared__ f16 BhL[128 * 32];
    __shared__ f16 BlL[128 * 32];

    const int tid = threadIdx.x;
    const int m0 = blockIdx.y * 128;
    const int n0 = blockIdx.x * 128;
    const int lane = tid & 63;
    const int wave = tid >> 6;
    const int wm = (wave >> 1) * 64;
    const int wn = (wave & 1) * 64;
    const int lr = lane & 15;          // fragment row (A) / col (B,D)
    const int fc = lane >> 4;          // fragment k-chunk 0..3 (8 halves each)

    // global_load_lds lane mapping within a 1024B wave-chunk (16 rows):
    const int grl = lane >> 2;                       // row-in-chunk 0..15
    const int gsc = (lane & 3) ^ ((lane >> 2) & 3);  // swizzled source chunk

    // manual A staging mapping (AFP32=1)
    const int sr = tid >> 2;           // row 0..63 (two passes)
    const int sc0 = tid & 3;           // logical chunk

    f32x4 acc[4][4];
    #pragma unroll
    for (int i = 0; i < 4; i++)
        #pragma unroll
        for (int j = 0; j < 4; j++)
            #pragma unroll
            for (int q = 0; q < 4; q++) acc[i][j][q] = 0.f;

    for (int k0 = 0; k0 < K; k0 += 32) {
        // ---- stage B (and A when f16) via global_load_lds, swizzled source ----
        #pragma unroll
        for (int p = 0; p < 2; p++) {
            const int ci = wave * 2 + p;             // chunk 0..7 (16 rows each)
            const int rl = (ci << 4) + grl;          // tile row 0..127
            const long bo = (long)(n0 + rl) * ldb + k0 + gsc * 8;
            gld16(Bhi + bo, BhL + ci * 512);
            gld16(Blo + bo, BlL + ci * 512);
            if constexpr (!AFP32) {
                const long ao = (long)(m0 + rl) * lda + k0 + gsc * 8;
                gld16(Ahi + ao, AhL + ci * 512);
                gld16(Alo + ao, AlL + ci * 512);
            }
        }
        if constexpr (AFP32) {
            // ---- A fp32: load, split, swizzled ds_write ----
            #pragma unroll
            for (int p = 0; p < 2; p++) {
                const int row = sr + p * 64;
                const float* s = Af + (long)(m0 + row) * lda + k0 + sc0 * 8;
                float4 v0 = *(const float4*)s;
                float4 v1 = *(const float4*)(s + 4);
                float vv[8] = {v0.x, v0.y, v0.z, v0.w, v1.x, v1.y, v1.z, v1.w};
                f16x8 hi, lo;
                #pragma unroll
                for (int e = 0; e < 8; e++) {
                    f16 h = (f16)vv[e];
                    hi[e] = h;
                    lo[e] = (f16)(vv[e] - (float)h);
                }
                const int off = SWZ(row, sc0);
                *(f16x8*)(AhL + off) = hi;
                *(f16x8*)(AlL + off) = lo;
            }
        }
        __syncthreads();

        f16x8 ah[4], al[4];
        #pragma unroll
        for (int i = 0; i < 4; i++) {
            const int r = wm + i * 16 + lr;
            const int off = SWZ(r, fc);
            ah[i] = *(const f16x8*)(AhL + off);
            al[i] = *(const f16x8*)(AlL + off);
        }
        #pragma unroll
        for (int j = 0; j < 4; j++) {
            const int r = wn + j * 16 + lr;
            const int off = SWZ(r, fc);
            f16x8 bh = *(const f16x8*)(BhL + off);
            f16x8 bl = *(const f16x8*)(BlL + off);
            #pragma unroll
            for (int i = 0; i < 4; i++) {
                acc[i][j] = __builtin_amdgcn_mfma_f32_16x16x32_f16(ah[i], bh, acc[i][j], 0, 0, 0);
                acc[i][j] = __builtin_amdgcn_mfma_f32_16x16x32_f16(ah[i], bl, acc[i][j], 0, 0, 0);
                acc[i][j] = __builtin_amdgcn_mfma_f32_16x16x32_f16(al[i], bh, acc[i][j], 0, 0, 0);
            }
        }
        __syncthreads();
    }

    // Epilogue. D layout (verified): col = lane&15, row = (lane>>4)*4 + reg.
    float* Cfb = Cf ? Cf + (long)bz * sC : nullptr;
    f16* Chb = Ch ? Ch + (long)bz * sC : nullptr;
    f16* Clb = Cl ? Cl + (long)bz * sC : nullptr;
    const int rq = (lane >> 4) * 4;
    #pragma unroll
    for (int i = 0; i < 4; i++) {
        #pragma unroll
        for (int j = 0; j < 4; j++) {
            const int ncol = n0 + wn + j * 16 + lr;
            const float bv = bias ? bias[ncol] : 0.f;
            #pragma unroll
            for (int q = 0; q < 4; q++) {
                const int mrow = m0 + wm + i * 16 + rq + q;
                float v = acc[i][j][q] * alpha + bv;
                if (relu) v = fmaxf(v, 0.f);
                const long idx = (long)mrow * ldc + ncol;
                if (Cfb) {
                    if (accum) v += Cfb[idx];
                    Cfb[idx] = v;
                } else {
                    f16 h = (f16)v;
                    Chb[idx] = h;
                    Clb[idx] = (f16)(v - (float)h);
                }
            }
        }
    }
}

// ---------------------------------------------------------------------------
// Weight convert: W [K,N] fp32 -> hi/lo f16 planes, transposed to [N,K].
// ---------------------------------------------------------------------------
__global__ __launch_bounds__(256) void wsplit_t(
    const float* __restrict__ w, f16* __restrict__ hi, f16* __restrict__ lo,
    int K, int N)
{
    int i = blockIdx.x * 256 + threadIdx.x;   // index over output [N,K]
    if (i >= N * K) return;
    int n = i / K, k = i - n * K;
    float v = w[(long)k * N + n];
    f16 h = (f16)v;
    hi[i] = h;
    lo[i] = (f16)(v - (float)h);
}

// ---------------------------------------------------------------------------
// LayerNorm over last dim (256): reads fp32 x, writes f16 hi/lo planes.
// ---------------------------------------------------------------------------
__global__ __launch_bounds__(256) void layernorm_split(
    const float* __restrict__ x, const float* __restrict__ g,
    const float* __restrict__ b, f16* __restrict__ nhi, f16* __restrict__ nlo)
{
    int tid = threadIdx.x;
    long row = (long)blockIdx.x * 4 + (tid >> 6);
    int lane = tid & 63;
    float4 v = ((const float4*)(x + row * DM))[lane];
    float s = v.x + v.y + v.z + v.w;
    float q = v.x * v.x + v.y * v.y + v.z * v.z + v.w * v.w;
    #pragma unroll
    for (int off = 32; off > 0; off >>= 1) {
        s += __shfl_xor(s, off);
        q += __shfl_xor(q, off);
    }
    float mu = s * (1.f / DM);
    float var = q * (1.f / DM) - mu * mu;
    float rs = rsqrtf(var + EPS);
    float4 gg = ((const float4*)g)[lane];
    float4 bb = ((const float4*)b)[lane];
    float o[4];
    o[0] = (v.x - mu) * rs * gg.x + bb.x;
    o[1] = (v.y - mu) * rs * gg.y + bb.y;
    o[2] = (v.z - mu) * rs * gg.z + bb.z;
    o[3] = (v.w - mu) * rs * gg.w + bb.w;
    f16x4 hi, lo;
    #pragma unroll
    for (int e = 0; e < 4; e++) {
        f16 h = (f16)o[e];
        hi[e] = h;
        lo[e] = (f16)(o[e] - (float)h);
    }
    ((f16x4*)(nhi + row * DM))[lane] = hi;
    ((f16x4*)(nlo + row * DM))[lane] = lo;
}

// ---------------------------------------------------------------------------
// Per-channel transpose of split planes: [S,D] -> [D,S], both hi and lo.
// ---------------------------------------------------------------------------
__global__ __launch_bounds__(256) void transpose_split(
    const f16* __restrict__ shi, const f16* __restrict__ slo,
    f16* __restrict__ dhi, f16* __restrict__ dlo)
{
    __shared__ f16 tl[2][64][72];
    const int c = blockIdx.z;
    const int d0 = blockIdx.x * 64;
    const int s0 = blockIdx.y * 64;
    const int t = threadIdx.x;
    const int rr = t >> 3;           // 0..31
    const int cc = (t & 7) * 8;
    const long base = (long)c * SD;
    #pragma unroll
    for (int p = 0; p < 2; p++) {
        int i = rr + p * 32;
        *(f16x8*)&tl[0][i][cc] = *(const f16x8*)(shi + base + (long)(s0 + i) * DM + d0 + cc);
        *(f16x8*)&tl[1][i][cc] = *(const f16x8*)(slo + base + (long)(s0 + i) * DM + d0 + cc);
    }
    __syncthreads();
    #pragma unroll
    for (int p = 0; p < 2; p++) {
        int i = rr + p * 32;         // d-local
        f16x8 vh, vl;
        #pragma unroll
        for (int e = 0; e < 8; e++) {
            vh[e] = tl[0][cc + e][i];
            vl[e] = tl[1][cc + e][i];
        }
        *(f16x8*)(dhi + base + (long)(d0 + i) * SEQ + s0 + cc) = vh;
        *(f16x8*)(dlo + base + (long)(d0 + i) * SEQ + s0 + cc) = vl;
    }
}

// ---------------------------------------------------------------------------
// Row softmax over width 512, in place.
// ---------------------------------------------------------------------------
__global__ __launch_bounds__(256) void softmax_k(float* __restrict__ a)
{
    int tid = threadIdx.x;
    long row = (long)blockIdx.x * 4 + (tid >> 6);
    int lane = tid & 63;
    float4* r = (float4*)(a + row * SEQ);
    float4 v0 = r[lane];
    float4 v1 = r[lane + 64];
    float m = fmaxf(fmaxf(fmaxf(v0.x, v0.y), fmaxf(v0.z, v0.w)),
                    fmaxf(fmaxf(v1.x, v1.y), fmaxf(v1.z, v1.w)));
    #pragma unroll
    for (int off = 32; off > 0; off >>= 1) m = fmaxf(m, __shfl_xor(m, off));
    v0.x = expf(v0.x - m); v0.y = expf(v0.y - m);
    v0.z = expf(v0.z - m); v0.w = expf(v0.w - m);
    v1.x = expf(v1.x - m); v1.y = expf(v1.y - m);
    v1.z = expf(v1.z - m); v1.w = expf(v1.w - m);
    float s = v0.x + v0.y + v0.z + v0.w + v1.x + v1.y + v1.z + v1.w;
    #pragma unroll
    for (int off = 32; off > 0; off >>= 1) s += __shfl_xor(s, off);
    float inv = 1.f / s;
    v0.x *= inv; v0.y *= inv; v0.z *= inv; v0.w *= inv;
    v1.x *= inv; v1.y *= inv; v1.z *= inv; v1.w *= inv;
    r[lane] = v0;
    r[lane + 64] = v1;
}

// ---------------------------------------------------------------------------
// Per-channel mean of h.
// ---------------------------------------------------------------------------
__global__ __launch_bounds__(256) void channel_mean_k(
    const float* __restrict__ h, float* __restrict__ y)
{
    __shared__ float red[256];
    int c = blockIdx.x;
    int tid = threadIdx.x;
    const float4* p = (const float4*)(h + (long)c * SEQ * DM);
    float s = 0.f;
    for (int i = tid; i < (SEQ * DM) / 4; i += 256) {
        float4 v = p[i];
        s += v.x + v.y + v.z + v.w;
    }
    red[tid] = s;
    __syncthreads();
    for (int off = 128; off > 0; off >>= 1) {
        if (tid < off) red[tid] += red[tid + off];
        __syncthreads();
    }
    if (tid == 0) y[c] = red[0] * (1.f / (SEQ * DM));
}

// ---------------------------------------------------------------------------
// SE MLP.
// ---------------------------------------------------------------------------
__global__ __launch_bounds__(256) void se_mlp_k(
    const float* __restrict__ y,
    const float* __restrict__ w1, const float* __restrict__ b1,
    const float* __restrict__ w2, const float* __restrict__ b2,
    float* __restrict__ g)
{
    __shared__ float z[16];
    int tid = threadIdx.x;
    if (tid < 16) {
        float s = b1[tid];
        for (int k = 0; k < CH; k++) s += y[k] * w1[k * 16 + tid];
        z[tid] = fmaxf(s, 0.f);
    }
    __syncthreads();
    float s = b2[tid];
    #pragma unroll
    for (int j = 0; j < 16; j++) s += z[j] * w2[j * CH + tid];
    g[tid] = 1.f / (1.f + expf(-s));
}

// ---------------------------------------------------------------------------
// Final: out = h * g[c] + x   (in place over h)
// ---------------------------------------------------------------------------
__global__ __launch_bounds__(256) void finalize_k(
    const float* __restrict__ h, const float* __restrict__ x,
    const float* __restrict__ g, float* __restrict__ out)
{
    long i = (long)blockIdx.x * 256 + threadIdx.x;   // float4 index
    int c = (int)(i >> 15) & 255;                    // i*4 / (S*D=2^17)
    float gv = g[c];
    float4 hv = ((const float4*)h)[i];
    float4 xv = ((const float4*)x)[i];
    float4 o;
    o.x = hv.x * gv + xv.x;
    o.y = hv.y * gv + xv.y;
    o.z = hv.z * gv + xv.z;
    o.w = hv.w * gv + xv.w;
    ((float4*)out)[i] = o;
}

// ---------------------------------------------------------------------------
extern "C" void kernel_launch(void* const* d_in, const int* in_sizes, int n_in,
                              void* d_out, int out_size, void* d_ws, size_t ws_size,
                              hipStream_t stream)
{
    const float* input = (const float*)d_in[0];
    const float* W_emb = (const float*)d_in[1];
    const float* b_emb = (const float*)d_in[2];
    const float* ln_g  = (const float*)d_in[3];
    const float* ln_b  = (const float*)d_in[4];
    const float* W1    = (const float*)d_in[5];
    const float* b1    = (const float*)d_in[6];
    const float* W2    = (const float*)d_in[7];
    const float* b2    = (const float*)d_in[8];
    const float* seW1  = (const float*)d_in[9];
    const float* seB1  = (const float*)d_in[10];
    const float* seW2  = (const float*)d_in[11];
    const float* seB2  = (const float*)d_in[12];

    float* outp = (float*)d_out;            // [B,C,S,D] (h lives here too)
    float* attn = outp + ELEMS;             // [B,C,S,S] fp32 (output #2)

    // ---- workspace: EXACTLY 3*ELEMS + 512 floats ----
    float* ws = (float*)d_ws;
    float* xbuf = ws;                               // unit0: fp32 residual
    f16* nA_hi  = (f16*)(ws + ELEMS);               // unit1: n planes -> later o planes
    f16* nA_lo  = nA_hi + ELEMS;
    f16* u2     = (f16*)(ws + 2 * ELEMS);           // unit2: time-shared (2*ELEMS halves)
    float* yg   = ws + 3 * ELEMS;                   // y[256], g[256]

    // unit2 phase A: wembT planes (dead after emb GEMM)
    f16* wembT_hi = u2;                             // [DM,DIN] 65536 halves each
    f16* wembT_lo = u2 + 65536;
    // unit2 phase B: nT planes (dead after PV GEMM)
    f16* nT_hi = u2;
    f16* nT_lo = u2 + ELEMS;
    // unit2 phase C: w1T/w2T planes + FFN hidden chunk
    f16* w1T_hi = u2;                               // [DH,DM] 262144 each
    f16* w1T_lo = w1T_hi + 262144;
    f16* w2T_hi = w1T_lo + 262144;                  // [DM,DH] 262144 each
    f16* w2T_lo = w2T_hi + 262144;
    f16* t_hi   = w2T_lo + 262144;                  // chunk planes
    const int rc = 65536;                           // 2 chunks cover MTOT
    f16* t_lo   = t_hi + (long)rc * DM;             // ends < 2*ELEMS halves

    // o planes reuse unit1 (nA dead after scores GEMM)
    f16* o_hi = nA_hi;
    f16* o_lo = nA_lo;

    // 0) split+transpose W_emb into unit2
    wsplit_t<<<(DIN * DM + 255) / 256, 256, 0, stream>>>(W_emb, wembT_hi, wembT_lo, DIN, DM);

    // 1) x = input @ W_emb + b_emb   (A fp32 split on the fly)
    gemm_mfma<1><<<dim3(DM / 128, MTOT / 128, 1), 256, 0, stream>>>(
        input, nullptr, wembT_hi, wembT_lo, xbuf, nullptr, nullptr, b_emb,
        MTOT, DM, DIN, DIN, DIN, DM, 0, 0, 0, 1.f, 0, 0);

    // 2) n = LayerNorm(x)  -> split planes (unit1)
    layernorm_split<<<MTOT / 4, 256, 0, stream>>>(xbuf, ln_g, ln_b, nA_hi, nA_lo);

    // 2b) n^T planes (unit2, overwrites dead wembT)
    transpose_split<<<dim3(DM / 64, SEQ / 64, CH), 256, 0, stream>>>(
        nA_hi, nA_lo, nT_hi, nT_lo);

    // 3a) scores = n @ n^T / 16   (B phys [N,K] == nA itself)
    gemm_mfma<0><<<dim3(SEQ / 128, SEQ / 128, CH), 256, 0, stream>>>(
        nA_hi, nA_lo, nA_hi, nA_lo, attn, nullptr, nullptr, nullptr,
        SEQ, SEQ, DM, DM, DM, SEQ, (long)SD, (long)SD, (long)SEQ * SEQ,
        1.f / 16.f, 0, 0);

    // 3b) softmax rows (in place, fp32 in d_out)
    softmax_k<<<(CH * SEQ) / 4, 256, 0, stream>>>(attn);

    // 3c) o = attn @ n   (A = attn fp32 split on the fly; B = nT planes)
    gemm_mfma<1><<<dim3(DM / 128, SEQ / 128, CH), 256, 0, stream>>>(
        attn, nullptr, nT_hi, nT_lo, nullptr, o_hi, o_lo, nullptr,
        SEQ, DM, SEQ, SEQ, SEQ, DM, (long)SEQ * SEQ, (long)SD, (long)SD,
        1.f, 0, 0);

    // 3d) split W1/W2 into unit2 (nT dead now)
    wsplit_t<<<(DM * DH + 255) / 256, 256, 0, stream>>>(W1, w1T_hi, w1T_lo, DM, DH);
    wsplit_t<<<(DH * DM + 255) / 256, 256, 0, stream>>>(W2, w2T_hi, w2T_lo, DH, DM);

    // 4) FFN: h = relu(o @ W1 + b1) @ W2 + b2   (hidden chunked by 256, h -> outp)
    for (int r0 = 0; r0 < MTOT; r0 += rc) {
        int rws = (MTOT - r0 < rc) ? (MTOT - r0) : rc;
        for (int hc = 0; hc < 4; hc++) {
            // t = relu(o_rows @ W1[:, hc*256:+256] + b1_chunk)  -> split planes
            gemm_mfma<0><<<dim3(2, rws / 128, 1), 256, 0, stream>>>(
                o_hi + (long)r0 * DM, o_lo + (long)r0 * DM,
                w1T_hi + (long)hc * 256 * DM, w1T_lo + (long)hc * 256 * DM,
                nullptr, t_hi, t_lo, b1 + hc * 256,
                rws, 256, DM, DM, DM, 256, 0, 0, 0, 1.f, 1, 0);
            // h += t @ W2[hc*256:+256, :]  (+b2 on first chunk)
            gemm_mfma<0><<<dim3(2, rws / 128, 1), 256, 0, stream>>>(
                t_hi, t_lo, w2T_hi + hc * 256, w2T_lo + hc * 256,
                outp + (long)r0 * DM, nullptr, nullptr, (hc == 0) ? b2 : nullptr,
                rws, DM, 256, 256, DH, DM, 0, 0, 0, 1.f, 0, (hc > 0) ? 1 : 0);
        }
    }

    // 5) SE gate (h is in outp)
    channel_mean_k<<<CH, 256, 0, stream>>>(outp, yg);
    se_mlp_k<<<1, 256, 0, stream>>>(yg, seW1, seB1, seW2, seB2, yg + 256);

    // 6) out = h * g + x  (in place over outp)
    finalize_k<<<(unsigned)(ELEMS / 4 / 256), 256, 0, stream>>>(
        outp, xbuf, yg + 256, outp);
}